// Round 6
// baseline (220.826 us; speedup 1.0000x reference)
//
#include <hip/hip_runtime.h>
#include <math.h>

// ---------------------------------------------------------------------------
// DRIGNNBCE R5: exact-packed counting-sort CSR build (512-node bins):
//   hist -> scanbins -> bin2 (block-reserved contiguous runs) -> sort3
//   (per-bin LDS counting sort, contiguous csr writes).
// Keeps: ballotless prop (4-rows-per-load ushort4), query-restricted layer 3.
// ---------------------------------------------------------------------------

__device__ __forceinline__ float bf2f(unsigned short h) {
    return __uint_as_float((unsigned)h << 16);
}
__device__ __forceinline__ unsigned short f2bf(float f) {
    unsigned u = __float_as_uint(f);
    return (unsigned short)((u + 0x7fffu + ((u >> 16) & 1u)) >> 16);
}

// ---- CSR build: 512-node bins, exact packing ----

__global__ void zero256_kernel(int* p) { p[threadIdx.x] = 0; }

__global__ __launch_bounds__(256) void hist_kernel(
    const int* __restrict__ dst, int* __restrict__ ghist, int E) {
    __shared__ int lh[256];
    lh[threadIdx.x] = 0;
    __syncthreads();
    for (int e = blockIdx.x * 256 + threadIdx.x; e < E; e += gridDim.x * 256)
        atomicAdd(&lh[dst[e] >> 9], 1);
    __syncthreads();
    int c = lh[threadIdx.x];
    if (c > 0) atomicAdd(&ghist[threadIdx.x], c);
}

// Single block: exclusive scan of 256 bin counts -> binbase, cursor2, off[N]=E.
__global__ __launch_bounds__(256) void scanbins_kernel(
    const int* __restrict__ ghist, int* __restrict__ binbase,
    int* __restrict__ cursor2, int* __restrict__ off, int N, int E) {
    __shared__ int ws[4];
    int lane = threadIdx.x & 63, wid = threadIdx.x >> 6;
    int own = ghist[threadIdx.x];
    int v = own;
    for (int o = 1; o < 64; o <<= 1) {
        int t = __shfl_up(v, o, 64);
        if (lane >= o) v += t;
    }
    if (lane == 63) ws[wid] = v;
    __syncthreads();
    int base = 0;
    for (int k = 0; k < 4; ++k) if (k < wid) base += ws[k];
    int excl = base + v - own;
    binbase[threadIdx.x] = excl;
    cursor2[threadIdx.x] = excl;
    if (threadIdx.x == 0) off[N] = E;
}

// Per 4096-edge block: LDS bin count, one global atomic per bin to reserve,
// LDS-cursor scatter -> contiguous per-(block,bin) runs in pairs2.
__global__ __launch_bounds__(256) void bin2_kernel(
    const int* __restrict__ src, const int* __restrict__ dst,
    int* __restrict__ cursor2, unsigned long long* __restrict__ pairs2, int E) {
    __shared__ int lcnt[256];
    __shared__ int lbase[256];
    int tid = threadIdx.x;
    int base = blockIdx.x * 4096;
    lcnt[tid] = 0;
    __syncthreads();
    #pragma unroll
    for (int i = 0; i < 16; ++i) {
        int e = base + i * 256 + tid;
        if (e < E) atomicAdd(&lcnt[dst[e] >> 9], 1);
    }
    __syncthreads();
    int c = lcnt[tid];
    lbase[tid] = (c > 0) ? atomicAdd(&cursor2[tid], c) : 0;
    __syncthreads();
    lcnt[tid] = 0;
    __syncthreads();
    #pragma unroll
    for (int i = 0; i < 16; ++i) {
        int e = base + i * 256 + tid;
        if (e < E) {
            int d = dst[e], s = src[e];
            int b = d >> 9;
            int r = atomicAdd(&lcnt[b], 1);
            pairs2[(size_t)lbase[b] + r] =
                ((unsigned long long)(unsigned)d << 32) | (unsigned)s;
        }
    }
}

// One block per bin: LDS counting sort of <=512 nodes; writes off/invd/csr
// all into contiguous regions.
__global__ __launch_bounds__(256) void sort3_kernel(
    const unsigned long long* __restrict__ pairs2,
    const int* __restrict__ ghist, const int* __restrict__ binbase,
    int* __restrict__ off, float* __restrict__ invd,
    int* __restrict__ csr, int N) {
    __shared__ int lcnt[512];
    __shared__ int wsum[8];
    int bin = blockIdx.x;
    int nodebase = bin << 9;
    int n = ghist[bin];
    int ebase = binbase[bin];
    const unsigned long long* p = pairs2 + ebase;
    int tid = threadIdx.x, lane = tid & 63, wid = tid >> 6;

    lcnt[tid] = 0;
    lcnt[tid + 256] = 0;
    __syncthreads();
    for (int i = tid; i < n; i += 256)
        atomicAdd(&lcnt[(int)(p[i] >> 32) - nodebase], 1);
    __syncthreads();

    // scan 512 counters: 8 chunks of 64; wave w owns chunks w and w+4
    int j0 = wid * 64 + lane, j1 = (wid + 4) * 64 + lane;
    int own0 = lcnt[j0], own1 = lcnt[j1];
    int v0 = own0, v1 = own1;
    for (int o = 1; o < 64; o <<= 1) {
        int t0 = __shfl_up(v0, o, 64);
        int t1 = __shfl_up(v1, o, 64);
        if (lane >= o) { v0 += t0; v1 += t1; }
    }
    if (lane == 63) { wsum[wid] = v0; wsum[wid + 4] = v1; }
    __syncthreads();
    int pre0 = 0, pre1 = 0;
    #pragma unroll
    for (int k = 0; k < 8; ++k) {
        int s = wsum[k];
        if (k < wid) pre0 += s;
        if (k < wid + 4) pre1 += s;
    }
    int e0 = pre0 + v0 - own0;   // exclusive local offset
    int e1 = pre1 + v1 - own1;
    __syncthreads();             // done reading lcnt as counts
    if (nodebase + j0 < N) {
        off[nodebase + j0] = ebase + e0;
        invd[nodebase + j0] = (own0 > 0) ? 1.0f / (float)own0 : 0.0f;
    }
    if (nodebase + j1 < N) {
        off[nodebase + j1] = ebase + e1;
        invd[nodebase + j1] = (own1 > 0) ? 1.0f / (float)own1 : 0.0f;
    }
    lcnt[j0] = e0;               // reuse as scatter cursor
    lcnt[j1] = e1;
    __syncthreads();
    for (int i = tid; i < n; i += 256) {
        unsigned long long pr = p[i];
        int d = (int)(pr >> 32), s = (int)(pr & 0xffffffffu);
        int pos = atomicAdd(&lcnt[d - nodebase], 1);
        csr[ebase + pos] = s;
    }
}

// ---- features / propagation ----

__global__ __launch_bounds__(256) void conv_kernel(
    const float* __restrict__ utab, const float* __restrict__ itab,
    unsigned short* __restrict__ fb, int total, int uElems) {
    int i = (blockIdx.x * blockDim.x + threadIdx.x) * 4;
    if (i >= total) return;
    const float* srcp = (i < uElems) ? (utab + i) : (itab + (i - uElems));
    float4 v = *(const float4*)srcp;
    ushort4 o;
    o.x = f2bf(v.x); o.y = f2bf(v.y); o.z = f2bf(v.z); o.w = f2bf(v.w);
    *(ushort4*)(fb + i) = o;
}

// One wave per node. Lane L: row-group g=L>>4, columns 4*(L&15)..+3.
__global__ __launch_bounds__(256) void prop_kernel(
    const unsigned short* __restrict__ cur,
    const int* __restrict__ off, const int* __restrict__ csr,
    const float* __restrict__ invd,
    unsigned short* __restrict__ nxt, int N) {
    int gw = (blockIdx.x * blockDim.x + threadIdx.x) >> 6;
    int lane = threadIdx.x & 63;
    if (gw >= N) return;
    int g = lane >> 4;
    int cL = lane & 15;
    int beg = off[gw], end = off[gw + 1];
    float ax = 0.f, ay = 0.f, az = 0.f, aw = 0.f;
    float bx = 0.f, by = 0.f, bz = 0.f, bw = 0.f;
    int p = beg;
    for (; p + 7 < end; p += 8) {
        int sA = csr[p + g];
        int sB = csr[p + 4 + g];
        ushort4 vA = *(const ushort4*)(cur + (size_t)sA * 64 + 4 * cL);
        ushort4 vB = *(const ushort4*)(cur + (size_t)sB * 64 + 4 * cL);
        ax += bf2f(vA.x); ay += bf2f(vA.y); az += bf2f(vA.z); aw += bf2f(vA.w);
        bx += bf2f(vB.x); by += bf2f(vB.y); bz += bf2f(vB.z); bw += bf2f(vB.w);
    }
    if (p + 3 < end) {
        int s = csr[p + g];
        ushort4 v = *(const ushort4*)(cur + (size_t)s * 64 + 4 * cL);
        ax += bf2f(v.x); ay += bf2f(v.y); az += bf2f(v.z); aw += bf2f(v.w);
        p += 4;
    }
    if (p < end) {
        int idx = p + g;
        int s = csr[(idx < end) ? idx : (end - 1)];
        float w = (idx < end) ? 1.f : 0.f;
        ushort4 v = *(const ushort4*)(cur + (size_t)s * 64 + 4 * cL);
        ax = fmaf(w, bf2f(v.x), ax); ay = fmaf(w, bf2f(v.y), ay);
        az = fmaf(w, bf2f(v.z), az); aw = fmaf(w, bf2f(v.w), aw);
    }
    ax += bx; ay += by; az += bz; aw += bw;
    ax += __shfl_xor(ax, 16, 64); ax += __shfl_xor(ax, 32, 64);
    ay += __shfl_xor(ay, 16, 64); ay += __shfl_xor(ay, 32, 64);
    az += __shfl_xor(az, 16, 64); az += __shfl_xor(az, 32, 64);
    aw += __shfl_xor(aw, 16, 64); aw += __shfl_xor(aw, 32, 64);
    if (g == 0) {
        float inv = invd[gw];
        ushort4 o;
        o.x = f2bf(ax * inv); o.y = f2bf(ay * inv);
        o.z = f2bf(az * inv); o.w = f2bf(aw * inv);
        *(ushort4*)(nxt + (size_t)gw * 64 + 4 * cL) = o;
    }
}

// Fused layer-3 restricted to query nodes.
__global__ __launch_bounds__(256) void prop3q_kernel(
    const unsigned short* __restrict__ cur,
    const int* __restrict__ uidx, const int* __restrict__ iidx,
    const int* __restrict__ off, const int* __restrict__ csr,
    const float* __restrict__ invd,
    float* __restrict__ uacc, float* __restrict__ iacc, int B, int NU) {
    int w = (blockIdx.x * blockDim.x + threadIdx.x) >> 6;
    if (w >= 2 * B) return;
    int lane = threadIdx.x & 63;
    int g = lane >> 4;
    int cL = lane & 15;
    int node;
    float* acc;
    if (w < B) { node = uidx[w]; acc = uacc + (size_t)w * 64; }
    else       { node = NU + iidx[w - B]; acc = iacc + (size_t)(w - B) * 64; }
    int beg = off[node], end = off[node + 1];
    float ax = 0.f, ay = 0.f, az = 0.f, aw = 0.f;
    float bx = 0.f, by = 0.f, bz = 0.f, bw = 0.f;
    int p = beg;
    for (; p + 7 < end; p += 8) {
        int sA = csr[p + g];
        int sB = csr[p + 4 + g];
        ushort4 vA = *(const ushort4*)(cur + (size_t)sA * 64 + 4 * cL);
        ushort4 vB = *(const ushort4*)(cur + (size_t)sB * 64 + 4 * cL);
        ax += bf2f(vA.x); ay += bf2f(vA.y); az += bf2f(vA.z); aw += bf2f(vA.w);
        bx += bf2f(vB.x); by += bf2f(vB.y); bz += bf2f(vB.z); bw += bf2f(vB.w);
    }
    if (p + 3 < end) {
        int s = csr[p + g];
        ushort4 v = *(const ushort4*)(cur + (size_t)s * 64 + 4 * cL);
        ax += bf2f(v.x); ay += bf2f(v.y); az += bf2f(v.z); aw += bf2f(v.w);
        p += 4;
    }
    if (p < end) {
        int idx = p + g;
        int s = csr[(idx < end) ? idx : (end - 1)];
        float wt = (idx < end) ? 1.f : 0.f;
        ushort4 v = *(const ushort4*)(cur + (size_t)s * 64 + 4 * cL);
        ax = fmaf(wt, bf2f(v.x), ax); ay = fmaf(wt, bf2f(v.y), ay);
        az = fmaf(wt, bf2f(v.z), az); aw = fmaf(wt, bf2f(v.w), aw);
    }
    ax += bx; ay += by; az += bz; aw += bw;
    ax += __shfl_xor(ax, 16, 64); ax += __shfl_xor(ax, 32, 64);
    ay += __shfl_xor(ay, 16, 64); ay += __shfl_xor(ay, 32, 64);
    az += __shfl_xor(az, 16, 64); az += __shfl_xor(az, 32, 64);
    aw += __shfl_xor(aw, 16, 64); aw += __shfl_xor(aw, 32, 64);
    if (g == 0) {
        float inv = invd[node];
        float4 prev = *(float4*)(acc + 4 * cL);
        prev.x += ax * inv; prev.y += ay * inv;
        prev.z += az * inv; prev.w += aw * inv;
        *(float4*)(acc + 4 * cL) = prev;
    }
}

__global__ __launch_bounds__(256) void qinit_kernel(
    const int* __restrict__ uidx, const int* __restrict__ iidx,
    const float* __restrict__ utab, const float* __restrict__ itab,
    float* __restrict__ uacc, float* __restrict__ iacc, int B) {
    int w = (blockIdx.x * blockDim.x + threadIdx.x) >> 6;
    int lane = threadIdx.x & 63;
    if (w >= 2 * B) return;
    if (w < B) {
        uacc[(size_t)w * 64 + lane] = utab[(size_t)uidx[w] * 64 + lane];
    } else {
        int b = w - B;
        iacc[(size_t)b * 64 + lane] = itab[(size_t)iidx[b] * 64 + lane];
    }
}

__global__ __launch_bounds__(256) void qadd_kernel(
    const int* __restrict__ uidx, const int* __restrict__ iidx,
    const unsigned short* __restrict__ feat,
    float* __restrict__ uacc, float* __restrict__ iacc, int B, int NU) {
    int w = (blockIdx.x * blockDim.x + threadIdx.x) >> 6;
    int lane = threadIdx.x & 63;
    if (w >= 2 * B) return;
    if (w < B) {
        uacc[(size_t)w * 64 + lane] += bf2f(feat[(size_t)uidx[w] * 64 + lane]);
    } else {
        int b = w - B;
        iacc[(size_t)b * 64 + lane] += bf2f(feat[((size_t)NU + iidx[b]) * 64 + lane]);
    }
}

__global__ __launch_bounds__(256) void dot_kernel(
    const float* __restrict__ uacc, const float* __restrict__ iacc,
    float* __restrict__ out0, int B) {
    int w = (blockIdx.x * blockDim.x + threadIdx.x) >> 6;
    int lane = threadIdx.x & 63;
    if (w >= B) return;
    float v = uacc[(size_t)w * 64 + lane] * iacc[(size_t)w * 64 + lane];
    for (int o = 32; o; o >>= 1) v += __shfl_down(v, o, 64);
    if (lane == 0) out0[w] = 1.0f / (1.0f + expf(-v * (1.0f / 16.0f)));
}

__global__ __launch_bounds__(256) void time_kernel(
    const int* __restrict__ uidx, const int* __restrict__ iidx,
    const float* __restrict__ utr, const float* __restrict__ itr,
    const float* __restrict__ utt, const float* __restrict__ itt,
    const float* __restrict__ utab, const float* __restrict__ itab,
    const float* __restrict__ W1, const float* __restrict__ b1,
    const float* __restrict__ W2, const float* __restrict__ b2,
    float* __restrict__ out1, float* __restrict__ regpart, int B) {
    __shared__ float sh[4][320];
    int wid = threadIdx.x >> 6, lane = threadIdx.x & 63;
    int b = blockIdx.x * 4 + wid;
    bool valid = (b < B);
    int bb = valid ? b : (B - 1);

    float* tu = sh[wid];
    float* ti = tu + 128;
    float* hu = ti + 128;
    float* hi = hu + 32;

    tu[lane]      = utr[(size_t)bb * 128 + lane];
    tu[lane + 64] = utr[(size_t)bb * 128 + 64 + lane];
    ti[lane]      = itr[(size_t)bb * 128 + lane];
    ti[lane + 64] = itr[(size_t)bb * 128 + 64 + lane];
    __syncthreads();

    {
        int j = lane & 31;
        const float* t = (lane < 32) ? tu : ti;
        float acc = b1[j];
        #pragma unroll 8
        for (int k = 0; k < 128; ++k) acc += t[k] * W1[k * 32 + j];
        float* h = (lane < 32) ? hu : hi;
        h[j] = fmaxf(acc, 0.0f);
    }
    __syncthreads();

    float mu0 = b2[lane], mu1 = b2[64 + lane];
    float mi0 = b2[lane], mi1 = b2[64 + lane];
    #pragma unroll 8
    for (int j = 0; j < 32; ++j) {
        float w0 = W2[j * 128 + lane], w1 = W2[j * 128 + 64 + lane];
        float huj = hu[j], hij = hi[j];
        mu0 += huj * w0; mu1 += huj * w1;
        mi0 += hij * w0; mi1 += hij * w1;
    }

    int u = uidx[bb], it = iidx[bb];
    const float* uterow = utt + (size_t)u * 256;
    const float* iterow = itt + (size_t)it * 256;
    float ute0 = uterow[lane], ute1 = uterow[64 + lane], ute2 = uterow[128 + lane], ute3 = uterow[192 + lane];
    float ite0 = iterow[lane], ite1 = iterow[64 + lane], ite2 = iterow[128 + lane], ite3 = iterow[192 + lane];

    float utm = ute0 * tu[lane] + ute1 * tu[64 + lane] + ute2 * mu0 + ute3 * mu1;
    float itm = ite0 * ti[lane] + ite1 * ti[64 + lane] + ite2 * mi0 + ite3 * mi1;

    float ue0 = utab[(size_t)u * 64 + lane], ie0 = itab[(size_t)it * 64 + lane];
    float reg = ute0 * ute0 + ute1 * ute1 + ute2 * ute2 + ute3 * ute3
              + ite0 * ite0 + ite1 * ite1 + ite2 * ite2 + ite3 * ite3
              + ue0 * ue0 + ie0 * ie0;

    float s = utm + itm;
    for (int o = 32; o; o >>= 1) {
        s   += __shfl_down(s, o, 64);
        reg += __shfl_down(reg, o, 64);
    }
    if (lane == 0 && valid) {
        out1[b] = 1.0f / (1.0f + expf(-s));
        regpart[b] = reg;
    }
}

__global__ __launch_bounds__(256) void regreduce_kernel(
    const float* __restrict__ regpart, float* __restrict__ out2, int B) {
    __shared__ float sh[256];
    float s = 0.0f;
    for (int i = threadIdx.x; i < B; i += 256) s += regpart[i];
    sh[threadIdx.x] = s;
    __syncthreads();
    for (int o = 128; o; o >>= 1) {
        if (threadIdx.x < (unsigned)o) sh[threadIdx.x] += sh[threadIdx.x + o];
        __syncthreads();
    }
    if (threadIdx.x == 0) out2[0] = 0.5f * sh[0] / (float)B;
}

extern "C" void kernel_launch(void* const* d_in, const int* in_sizes, int n_in,
                              void* d_out, int out_size, void* d_ws, size_t ws_size,
                              hipStream_t stream) {
    const int*   uidx = (const int*)d_in[0];
    const int*   iidx = (const int*)d_in[1];
    const float* utr  = (const float*)d_in[3];
    const float* itr  = (const float*)d_in[4];
    const float* utab = (const float*)d_in[5];
    const float* itab = (const float*)d_in[6];
    const float* utt  = (const float*)d_in[7];
    const float* itt  = (const float*)d_in[8];
    const float* W1   = (const float*)d_in[9];
    const float* b1   = (const float*)d_in[10];
    const float* W2   = (const float*)d_in[11];
    const float* b2   = (const float*)d_in[12];
    const int*   esrc = (const int*)d_in[13];
    const int*   edst = (const int*)d_in[14];

    const int B  = in_sizes[0];
    const int H  = in_sizes[10];              // 32
    const int TT = in_sizes[9] / H;           // 128
    const int TM = TT + in_sizes[12];         // 256
    const int NU = in_sizes[7] / TM;          // 60000
    const int NI = in_sizes[8] / TM;          // 40000
    const int N  = NU + NI;                   // 100000
    const int E  = in_sizes[13];              // 1600000
    const int D  = 64;
    const int nbin = (N + 511) >> 9;          // 196 (<=256 for N<=131072)

    // ---- workspace carve-up (256B aligned) ----
    char* ws = (char*)d_ws;
    size_t o = 0;
    auto carve = [&](size_t bytes) -> char* {
        char* p = ws + o;
        o = (o + bytes + 255) & ~(size_t)255;
        return p;
    };
    unsigned short* fb0 = (unsigned short*)carve((size_t)N * D * sizeof(unsigned short));
    // fb1 region doubles as pairs2 (E u64). Dead before fb1 first written:
    // sort3 finishes reading pairs2 before prop #1 writes fb1.
    size_t fb1Bytes = (size_t)N * D * sizeof(unsigned short);
    size_t p2Bytes  = (size_t)E * sizeof(unsigned long long);
    unsigned short* fb1 = (unsigned short*)carve(fb1Bytes > p2Bytes ? fb1Bytes : p2Bytes);
    float* uacc    = (float*)carve((size_t)B * D * sizeof(float));
    float* iacc    = (float*)carve((size_t)B * D * sizeof(float));
    float* invd    = (float*)carve((size_t)N * sizeof(float));
    int*   off     = (int*)  carve((size_t)(N + 1) * sizeof(int));
    int*   csr     = (int*)  carve((size_t)E * sizeof(int));
    int*   ghist   = (int*)  carve(256 * sizeof(int));
    int*   binbase = (int*)  carve(256 * sizeof(int));
    int*   cursor2 = (int*)  carve(256 * sizeof(int));
    float* regpart = (float*)carve((size_t)B * sizeof(float));
    (void)ws_size;

    unsigned long long* pairs2 = (unsigned long long*)fb1;  // alias

    float* out0 = (float*)d_out;          // [B]
    float* out1 = out0 + B;               // [B]
    float* out2 = out1 + B;               // [1]

    // ---- CSR build (exact-packed counting sort) ----
    zero256_kernel<<<1, 256, 0, stream>>>(ghist);
    hist_kernel<<<512, 256, 0, stream>>>(edst, ghist, E);
    scanbins_kernel<<<1, 256, 0, stream>>>(ghist, binbase, cursor2, off, N, E);
    bin2_kernel<<<(E + 4095) / 4096, 256, 0, stream>>>(esrc, edst, cursor2, pairs2, E);
    sort3_kernel<<<nbin, 256, 0, stream>>>(pairs2, ghist, binbase, off, invd, csr, N);
    // pairs2 (fb1 alias) dead from here on.

    // ---- bf16 feature buffer (layer 0) ----
    conv_kernel<<<(N * D / 4 + 255) / 256, 256, 0, stream>>>(utab, itab, fb0, N * D, NU * D);

    // ---- query accumulators ----
    qinit_kernel<<<(2 * B * 64 + 255) / 256, 256, 0, stream>>>(uidx, iidx, utab, itab, uacc, iacc, B);

    // ---- propagation: layers 1,2 full; layer 3 query-restricted ----
    const int prop_blocks = (N * 64 + 255) / 256;
    const int q_blocks = (2 * B * 64 + 255) / 256;
    prop_kernel<<<prop_blocks, 256, 0, stream>>>(fb0, off, csr, invd, fb1, N);
    qadd_kernel<<<q_blocks, 256, 0, stream>>>(uidx, iidx, fb1, uacc, iacc, B, NU);
    prop_kernel<<<prop_blocks, 256, 0, stream>>>(fb1, off, csr, invd, fb0, N);
    qadd_kernel<<<q_blocks, 256, 0, stream>>>(uidx, iidx, fb0, uacc, iacc, B, NU);
    prop3q_kernel<<<q_blocks, 256, 0, stream>>>(fb0, uidx, iidx, off, csr, invd, uacc, iacc, B, NU);

    // ---- outputs ----
    dot_kernel<<<(B * 64 + 255) / 256, 256, 0, stream>>>(uacc, iacc, out0, B);
    time_kernel<<<(B + 3) / 4, 256, 0, stream>>>(uidx, iidx, utr, itr, utt, itt, utab, itab,
                                                 W1, b1, W2, b2, out1, regpart, B);
    regreduce_kernel<<<1, 256, 0, stream>>>(regpart, out2, B);
}

// Round 7
// 220.318 us; speedup vs baseline: 1.0023x; 1.0023x over previous
//
#include <hip/hip_runtime.h>
#include <math.h>

// ---------------------------------------------------------------------------
// DRIGNNBCE R5: exact-packed counting-sort CSR build (512-node bins):
//   hist -> scanbins -> bin2 (block-reserved contiguous runs) -> sort3
//   (per-bin LDS counting sort, contiguous csr writes).
// Keeps: ballotless prop (4-rows-per-load ushort4), query-restricted layer 3.
// ---------------------------------------------------------------------------

__device__ __forceinline__ float bf2f(unsigned short h) {
    return __uint_as_float((unsigned)h << 16);
}
__device__ __forceinline__ unsigned short f2bf(float f) {
    unsigned u = __float_as_uint(f);
    return (unsigned short)((u + 0x7fffu + ((u >> 16) & 1u)) >> 16);
}

// ---- CSR build: 512-node bins, exact packing ----

__global__ void zero256_kernel(int* p) { p[threadIdx.x] = 0; }

__global__ __launch_bounds__(256) void hist_kernel(
    const int* __restrict__ dst, int* __restrict__ ghist, int E) {
    __shared__ int lh[256];
    lh[threadIdx.x] = 0;
    __syncthreads();
    for (int e = blockIdx.x * 256 + threadIdx.x; e < E; e += gridDim.x * 256)
        atomicAdd(&lh[dst[e] >> 9], 1);
    __syncthreads();
    int c = lh[threadIdx.x];
    if (c > 0) atomicAdd(&ghist[threadIdx.x], c);
}

// Single block: exclusive scan of 256 bin counts -> binbase, cursor2, off[N]=E.
__global__ __launch_bounds__(256) void scanbins_kernel(
    const int* __restrict__ ghist, int* __restrict__ binbase,
    int* __restrict__ cursor2, int* __restrict__ off, int N, int E) {
    __shared__ int ws[4];
    int lane = threadIdx.x & 63, wid = threadIdx.x >> 6;
    int own = ghist[threadIdx.x];
    int v = own;
    for (int o = 1; o < 64; o <<= 1) {
        int t = __shfl_up(v, o, 64);
        if (lane >= o) v += t;
    }
    if (lane == 63) ws[wid] = v;
    __syncthreads();
    int base = 0;
    for (int k = 0; k < 4; ++k) if (k < wid) base += ws[k];
    int excl = base + v - own;
    binbase[threadIdx.x] = excl;
    cursor2[threadIdx.x] = excl;
    if (threadIdx.x == 0) off[N] = E;
}

// Per 4096-edge block: LDS bin count, one global atomic per bin to reserve,
// LDS-cursor scatter -> contiguous per-(block,bin) runs in pairs2.
__global__ __launch_bounds__(256) void bin2_kernel(
    const int* __restrict__ src, const int* __restrict__ dst,
    int* __restrict__ cursor2, unsigned long long* __restrict__ pairs2, int E) {
    __shared__ int lcnt[256];
    __shared__ int lbase[256];
    int tid = threadIdx.x;
    int base = blockIdx.x * 4096;
    lcnt[tid] = 0;
    __syncthreads();
    #pragma unroll
    for (int i = 0; i < 16; ++i) {
        int e = base + i * 256 + tid;
        if (e < E) atomicAdd(&lcnt[dst[e] >> 9], 1);
    }
    __syncthreads();
    int c = lcnt[tid];
    lbase[tid] = (c > 0) ? atomicAdd(&cursor2[tid], c) : 0;
    __syncthreads();
    lcnt[tid] = 0;
    __syncthreads();
    #pragma unroll
    for (int i = 0; i < 16; ++i) {
        int e = base + i * 256 + tid;
        if (e < E) {
            int d = dst[e], s = src[e];
            int b = d >> 9;
            int r = atomicAdd(&lcnt[b], 1);
            pairs2[(size_t)lbase[b] + r] =
                ((unsigned long long)(unsigned)d << 32) | (unsigned)s;
        }
    }
}

// One block per bin: LDS counting sort of <=512 nodes; writes off/invd/csr
// all into contiguous regions.
__global__ __launch_bounds__(256) void sort3_kernel(
    const unsigned long long* __restrict__ pairs2,
    const int* __restrict__ ghist, const int* __restrict__ binbase,
    int* __restrict__ off, float* __restrict__ invd,
    int* __restrict__ csr, int N) {
    __shared__ int lcnt[512];
    __shared__ int wsum[8];
    int bin = blockIdx.x;
    int nodebase = bin << 9;
    int n = ghist[bin];
    int ebase = binbase[bin];
    const unsigned long long* p = pairs2 + ebase;
    int tid = threadIdx.x, lane = tid & 63, wid = tid >> 6;

    lcnt[tid] = 0;
    lcnt[tid + 256] = 0;
    __syncthreads();
    for (int i = tid; i < n; i += 256)
        atomicAdd(&lcnt[(int)(p[i] >> 32) - nodebase], 1);
    __syncthreads();

    // scan 512 counters: 8 chunks of 64; wave w owns chunks w and w+4
    int j0 = wid * 64 + lane, j1 = (wid + 4) * 64 + lane;
    int own0 = lcnt[j0], own1 = lcnt[j1];
    int v0 = own0, v1 = own1;
    for (int o = 1; o < 64; o <<= 1) {
        int t0 = __shfl_up(v0, o, 64);
        int t1 = __shfl_up(v1, o, 64);
        if (lane >= o) { v0 += t0; v1 += t1; }
    }
    if (lane == 63) { wsum[wid] = v0; wsum[wid + 4] = v1; }
    __syncthreads();
    int pre0 = 0, pre1 = 0;
    #pragma unroll
    for (int k = 0; k < 8; ++k) {
        int s = wsum[k];
        if (k < wid) pre0 += s;
        if (k < wid + 4) pre1 += s;
    }
    int e0 = pre0 + v0 - own0;   // exclusive local offset
    int e1 = pre1 + v1 - own1;
    __syncthreads();             // done reading lcnt as counts
    if (nodebase + j0 < N) {
        off[nodebase + j0] = ebase + e0;
        invd[nodebase + j0] = (own0 > 0) ? 1.0f / (float)own0 : 0.0f;
    }
    if (nodebase + j1 < N) {
        off[nodebase + j1] = ebase + e1;
        invd[nodebase + j1] = (own1 > 0) ? 1.0f / (float)own1 : 0.0f;
    }
    lcnt[j0] = e0;               // reuse as scatter cursor
    lcnt[j1] = e1;
    __syncthreads();
    for (int i = tid; i < n; i += 256) {
        unsigned long long pr = p[i];
        int d = (int)(pr >> 32), s = (int)(pr & 0xffffffffu);
        int pos = atomicAdd(&lcnt[d - nodebase], 1);
        csr[ebase + pos] = s;
    }
}

// ---- features / propagation ----

__global__ __launch_bounds__(256) void conv_kernel(
    const float* __restrict__ utab, const float* __restrict__ itab,
    unsigned short* __restrict__ fb, int total, int uElems) {
    int i = (blockIdx.x * blockDim.x + threadIdx.x) * 4;
    if (i >= total) return;
    const float* srcp = (i < uElems) ? (utab + i) : (itab + (i - uElems));
    float4 v = *(const float4*)srcp;
    ushort4 o;
    o.x = f2bf(v.x); o.y = f2bf(v.y); o.z = f2bf(v.z); o.w = f2bf(v.w);
    *(ushort4*)(fb + i) = o;
}

// One wave per node. Lane L: row-group g=L>>4, columns 4*(L&15)..+3.
__global__ __launch_bounds__(256) void prop_kernel(
    const unsigned short* __restrict__ cur,
    const int* __restrict__ off, const int* __restrict__ csr,
    const float* __restrict__ invd,
    unsigned short* __restrict__ nxt, int N) {
    int gw = (blockIdx.x * blockDim.x + threadIdx.x) >> 6;
    int lane = threadIdx.x & 63;
    if (gw >= N) return;
    int g = lane >> 4;
    int cL = lane & 15;
    int beg = off[gw], end = off[gw + 1];
    float ax = 0.f, ay = 0.f, az = 0.f, aw = 0.f;
    float bx = 0.f, by = 0.f, bz = 0.f, bw = 0.f;
    int p = beg;
    for (; p + 7 < end; p += 8) {
        int sA = csr[p + g];
        int sB = csr[p + 4 + g];
        ushort4 vA = *(const ushort4*)(cur + (size_t)sA * 64 + 4 * cL);
        ushort4 vB = *(const ushort4*)(cur + (size_t)sB * 64 + 4 * cL);
        ax += bf2f(vA.x); ay += bf2f(vA.y); az += bf2f(vA.z); aw += bf2f(vA.w);
        bx += bf2f(vB.x); by += bf2f(vB.y); bz += bf2f(vB.z); bw += bf2f(vB.w);
    }
    if (p + 3 < end) {
        int s = csr[p + g];
        ushort4 v = *(const ushort4*)(cur + (size_t)s * 64 + 4 * cL);
        ax += bf2f(v.x); ay += bf2f(v.y); az += bf2f(v.z); aw += bf2f(v.w);
        p += 4;
    }
    if (p < end) {
        int idx = p + g;
        int s = csr[(idx < end) ? idx : (end - 1)];
        float w = (idx < end) ? 1.f : 0.f;
        ushort4 v = *(const ushort4*)(cur + (size_t)s * 64 + 4 * cL);
        ax = fmaf(w, bf2f(v.x), ax); ay = fmaf(w, bf2f(v.y), ay);
        az = fmaf(w, bf2f(v.z), az); aw = fmaf(w, bf2f(v.w), aw);
    }
    ax += bx; ay += by; az += bz; aw += bw;
    ax += __shfl_xor(ax, 16, 64); ax += __shfl_xor(ax, 32, 64);
    ay += __shfl_xor(ay, 16, 64); ay += __shfl_xor(ay, 32, 64);
    az += __shfl_xor(az, 16, 64); az += __shfl_xor(az, 32, 64);
    aw += __shfl_xor(aw, 16, 64); aw += __shfl_xor(aw, 32, 64);
    if (g == 0) {
        float inv = invd[gw];
        ushort4 o;
        o.x = f2bf(ax * inv); o.y = f2bf(ay * inv);
        o.z = f2bf(az * inv); o.w = f2bf(aw * inv);
        *(ushort4*)(nxt + (size_t)gw * 64 + 4 * cL) = o;
    }
}

// Fused layer-3 restricted to query nodes.
__global__ __launch_bounds__(256) void prop3q_kernel(
    const unsigned short* __restrict__ cur,
    const int* __restrict__ uidx, const int* __restrict__ iidx,
    const int* __restrict__ off, const int* __restrict__ csr,
    const float* __restrict__ invd,
    float* __restrict__ uacc, float* __restrict__ iacc, int B, int NU) {
    int w = (blockIdx.x * blockDim.x + threadIdx.x) >> 6;
    if (w >= 2 * B) return;
    int lane = threadIdx.x & 63;
    int g = lane >> 4;
    int cL = lane & 15;
    int node;
    float* acc;
    if (w < B) { node = uidx[w]; acc = uacc + (size_t)w * 64; }
    else       { node = NU + iidx[w - B]; acc = iacc + (size_t)(w - B) * 64; }
    int beg = off[node], end = off[node + 1];
    float ax = 0.f, ay = 0.f, az = 0.f, aw = 0.f;
    float bx = 0.f, by = 0.f, bz = 0.f, bw = 0.f;
    int p = beg;
    for (; p + 7 < end; p += 8) {
        int sA = csr[p + g];
        int sB = csr[p + 4 + g];
        ushort4 vA = *(const ushort4*)(cur + (size_t)sA * 64 + 4 * cL);
        ushort4 vB = *(const ushort4*)(cur + (size_t)sB * 64 + 4 * cL);
        ax += bf2f(vA.x); ay += bf2f(vA.y); az += bf2f(vA.z); aw += bf2f(vA.w);
        bx += bf2f(vB.x); by += bf2f(vB.y); bz += bf2f(vB.z); bw += bf2f(vB.w);
    }
    if (p + 3 < end) {
        int s = csr[p + g];
        ushort4 v = *(const ushort4*)(cur + (size_t)s * 64 + 4 * cL);
        ax += bf2f(v.x); ay += bf2f(v.y); az += bf2f(v.z); aw += bf2f(v.w);
        p += 4;
    }
    if (p < end) {
        int idx = p + g;
        int s = csr[(idx < end) ? idx : (end - 1)];
        float wt = (idx < end) ? 1.f : 0.f;
        ushort4 v = *(const ushort4*)(cur + (size_t)s * 64 + 4 * cL);
        ax = fmaf(wt, bf2f(v.x), ax); ay = fmaf(wt, bf2f(v.y), ay);
        az = fmaf(wt, bf2f(v.z), az); aw = fmaf(wt, bf2f(v.w), aw);
    }
    ax += bx; ay += by; az += bz; aw += bw;
    ax += __shfl_xor(ax, 16, 64); ax += __shfl_xor(ax, 32, 64);
    ay += __shfl_xor(ay, 16, 64); ay += __shfl_xor(ay, 32, 64);
    az += __shfl_xor(az, 16, 64); az += __shfl_xor(az, 32, 64);
    aw += __shfl_xor(aw, 16, 64); aw += __shfl_xor(aw, 32, 64);
    if (g == 0) {
        float inv = invd[node];
        float4 prev = *(float4*)(acc + 4 * cL);
        prev.x += ax * inv; prev.y += ay * inv;
        prev.z += az * inv; prev.w += aw * inv;
        *(float4*)(acc + 4 * cL) = prev;
    }
}

__global__ __launch_bounds__(256) void qinit_kernel(
    const int* __restrict__ uidx, const int* __restrict__ iidx,
    const float* __restrict__ utab, const float* __restrict__ itab,
    float* __restrict__ uacc, float* __restrict__ iacc, int B) {
    int w = (blockIdx.x * blockDim.x + threadIdx.x) >> 6;
    int lane = threadIdx.x & 63;
    if (w >= 2 * B) return;
    if (w < B) {
        uacc[(size_t)w * 64 + lane] = utab[(size_t)uidx[w] * 64 + lane];
    } else {
        int b = w - B;
        iacc[(size_t)b * 64 + lane] = itab[(size_t)iidx[b] * 64 + lane];
    }
}

__global__ __launch_bounds__(256) void qadd_kernel(
    const int* __restrict__ uidx, const int* __restrict__ iidx,
    const unsigned short* __restrict__ feat,
    float* __restrict__ uacc, float* __restrict__ iacc, int B, int NU) {
    int w = (blockIdx.x * blockDim.x + threadIdx.x) >> 6;
    int lane = threadIdx.x & 63;
    if (w >= 2 * B) return;
    if (w < B) {
        uacc[(size_t)w * 64 + lane] += bf2f(feat[(size_t)uidx[w] * 64 + lane]);
    } else {
        int b = w - B;
        iacc[(size_t)b * 64 + lane] += bf2f(feat[((size_t)NU + iidx[b]) * 64 + lane]);
    }
}

__global__ __launch_bounds__(256) void dot_kernel(
    const float* __restrict__ uacc, const float* __restrict__ iacc,
    float* __restrict__ out0, int B) {
    int w = (blockIdx.x * blockDim.x + threadIdx.x) >> 6;
    int lane = threadIdx.x & 63;
    if (w >= B) return;
    float v = uacc[(size_t)w * 64 + lane] * iacc[(size_t)w * 64 + lane];
    for (int o = 32; o; o >>= 1) v += __shfl_down(v, o, 64);
    if (lane == 0) out0[w] = 1.0f / (1.0f + expf(-v * (1.0f / 16.0f)));
}

__global__ __launch_bounds__(256) void time_kernel(
    const int* __restrict__ uidx, const int* __restrict__ iidx,
    const float* __restrict__ utr, const float* __restrict__ itr,
    const float* __restrict__ utt, const float* __restrict__ itt,
    const float* __restrict__ utab, const float* __restrict__ itab,
    const float* __restrict__ W1, const float* __restrict__ b1,
    const float* __restrict__ W2, const float* __restrict__ b2,
    float* __restrict__ out1, float* __restrict__ regpart, int B) {
    __shared__ float sh[4][320];
    int wid = threadIdx.x >> 6, lane = threadIdx.x & 63;
    int b = blockIdx.x * 4 + wid;
    bool valid = (b < B);
    int bb = valid ? b : (B - 1);

    float* tu = sh[wid];
    float* ti = tu + 128;
    float* hu = ti + 128;
    float* hi = hu + 32;

    tu[lane]      = utr[(size_t)bb * 128 + lane];
    tu[lane + 64] = utr[(size_t)bb * 128 + 64 + lane];
    ti[lane]      = itr[(size_t)bb * 128 + lane];
    ti[lane + 64] = itr[(size_t)bb * 128 + 64 + lane];
    __syncthreads();

    {
        int j = lane & 31;
        const float* t = (lane < 32) ? tu : ti;
        float acc = b1[j];
        #pragma unroll 8
        for (int k = 0; k < 128; ++k) acc += t[k] * W1[k * 32 + j];
        float* h = (lane < 32) ? hu : hi;
        h[j] = fmaxf(acc, 0.0f);
    }
    __syncthreads();

    float mu0 = b2[lane], mu1 = b2[64 + lane];
    float mi0 = b2[lane], mi1 = b2[64 + lane];
    #pragma unroll 8
    for (int j = 0; j < 32; ++j) {
        float w0 = W2[j * 128 + lane], w1 = W2[j * 128 + 64 + lane];
        float huj = hu[j], hij = hi[j];
        mu0 += huj * w0; mu1 += huj * w1;
        mi0 += hij * w0; mi1 += hij * w1;
    }

    int u = uidx[bb], it = iidx[bb];
    const float* uterow = utt + (size_t)u * 256;
    const float* iterow = itt + (size_t)it * 256;
    float ute0 = uterow[lane], ute1 = uterow[64 + lane], ute2 = uterow[128 + lane], ute3 = uterow[192 + lane];
    float ite0 = iterow[lane], ite1 = iterow[64 + lane], ite2 = iterow[128 + lane], ite3 = iterow[192 + lane];

    float utm = ute0 * tu[lane] + ute1 * tu[64 + lane] + ute2 * mu0 + ute3 * mu1;
    float itm = ite0 * ti[lane] + ite1 * ti[64 + lane] + ite2 * mi0 + ite3 * mi1;

    float ue0 = utab[(size_t)u * 64 + lane], ie0 = itab[(size_t)it * 64 + lane];
    float reg = ute0 * ute0 + ute1 * ute1 + ute2 * ute2 + ute3 * ute3
              + ite0 * ite0 + ite1 * ite1 + ite2 * ite2 + ite3 * ite3
              + ue0 * ue0 + ie0 * ie0;

    float s = utm + itm;
    for (int o = 32; o; o >>= 1) {
        s   += __shfl_down(s, o, 64);
        reg += __shfl_down(reg, o, 64);
    }
    if (lane == 0 && valid) {
        out1[b] = 1.0f / (1.0f + expf(-s));
        regpart[b] = reg;
    }
}

__global__ __launch_bounds__(256) void regreduce_kernel(
    const float* __restrict__ regpart, float* __restrict__ out2, int B) {
    __shared__ float sh[256];
    float s = 0.0f;
    for (int i = threadIdx.x; i < B; i += 256) s += regpart[i];
    sh[threadIdx.x] = s;
    __syncthreads();
    for (int o = 128; o; o >>= 1) {
        if (threadIdx.x < (unsigned)o) sh[threadIdx.x] += sh[threadIdx.x + o];
        __syncthreads();
    }
    if (threadIdx.x == 0) out2[0] = 0.5f * sh[0] / (float)B;
}

extern "C" void kernel_launch(void* const* d_in, const int* in_sizes, int n_in,
                              void* d_out, int out_size, void* d_ws, size_t ws_size,
                              hipStream_t stream) {
    const int*   uidx = (const int*)d_in[0];
    const int*   iidx = (const int*)d_in[1];
    const float* utr  = (const float*)d_in[3];
    const float* itr  = (const float*)d_in[4];
    const float* utab = (const float*)d_in[5];
    const float* itab = (const float*)d_in[6];
    const float* utt  = (const float*)d_in[7];
    const float* itt  = (const float*)d_in[8];
    const float* W1   = (const float*)d_in[9];
    const float* b1   = (const float*)d_in[10];
    const float* W2   = (const float*)d_in[11];
    const float* b2   = (const float*)d_in[12];
    const int*   esrc = (const int*)d_in[13];
    const int*   edst = (const int*)d_in[14];

    const int B  = in_sizes[0];
    const int H  = in_sizes[10];              // 32
    const int TT = in_sizes[9] / H;           // 128
    const int TM = TT + in_sizes[12];         // 256
    const int NU = in_sizes[7] / TM;          // 60000
    const int NI = in_sizes[8] / TM;          // 40000
    const int N  = NU + NI;                   // 100000
    const int E  = in_sizes[13];              // 1600000
    const int D  = 64;
    const int nbin = (N + 511) >> 9;          // 196 (<=256 for N<=131072)

    // ---- workspace carve-up (256B aligned) ----
    char* ws = (char*)d_ws;
    size_t o = 0;
    auto carve = [&](size_t bytes) -> char* {
        char* p = ws + o;
        o = (o + bytes + 255) & ~(size_t)255;
        return p;
    };
    unsigned short* fb0 = (unsigned short*)carve((size_t)N * D * sizeof(unsigned short));
    // fb1 region doubles as pairs2 (E u64). Dead before fb1 first written:
    // sort3 finishes reading pairs2 before prop #1 writes fb1.
    size_t fb1Bytes = (size_t)N * D * sizeof(unsigned short);
    size_t p2Bytes  = (size_t)E * sizeof(unsigned long long);
    unsigned short* fb1 = (unsigned short*)carve(fb1Bytes > p2Bytes ? fb1Bytes : p2Bytes);
    float* uacc    = (float*)carve((size_t)B * D * sizeof(float));
    float* iacc    = (float*)carve((size_t)B * D * sizeof(float));
    float* invd    = (float*)carve((size_t)N * sizeof(float));
    int*   off     = (int*)  carve((size_t)(N + 1) * sizeof(int));
    int*   csr     = (int*)  carve((size_t)E * sizeof(int));
    int*   ghist   = (int*)  carve(256 * sizeof(int));
    int*   binbase = (int*)  carve(256 * sizeof(int));
    int*   cursor2 = (int*)  carve(256 * sizeof(int));
    float* regpart = (float*)carve((size_t)B * sizeof(float));
    (void)ws_size;

    unsigned long long* pairs2 = (unsigned long long*)fb1;  // alias

    float* out0 = (float*)d_out;          // [B]
    float* out1 = out0 + B;               // [B]
    float* out2 = out1 + B;               // [1]

    // ---- CSR build (exact-packed counting sort) ----
    zero256_kernel<<<1, 256, 0, stream>>>(ghist);
    hist_kernel<<<512, 256, 0, stream>>>(edst, ghist, E);
    scanbins_kernel<<<1, 256, 0, stream>>>(ghist, binbase, cursor2, off, N, E);
    bin2_kernel<<<(E + 4095) / 4096, 256, 0, stream>>>(esrc, edst, cursor2, pairs2, E);
    sort3_kernel<<<nbin, 256, 0, stream>>>(pairs2, ghist, binbase, off, invd, csr, N);
    // pairs2 (fb1 alias) dead from here on.

    // ---- bf16 feature buffer (layer 0) ----
    conv_kernel<<<(N * D / 4 + 255) / 256, 256, 0, stream>>>(utab, itab, fb0, N * D, NU * D);

    // ---- query accumulators ----
    qinit_kernel<<<(2 * B * 64 + 255) / 256, 256, 0, stream>>>(uidx, iidx, utab, itab, uacc, iacc, B);

    // ---- propagation: layers 1,2 full; layer 3 query-restricted ----
    const int prop_blocks = (N * 64 + 255) / 256;
    const int q_blocks = (2 * B * 64 + 255) / 256;
    prop_kernel<<<prop_blocks, 256, 0, stream>>>(fb0, off, csr, invd, fb1, N);
    qadd_kernel<<<q_blocks, 256, 0, stream>>>(uidx, iidx, fb1, uacc, iacc, B, NU);
    prop_kernel<<<prop_blocks, 256, 0, stream>>>(fb1, off, csr, invd, fb0, N);
    qadd_kernel<<<q_blocks, 256, 0, stream>>>(uidx, iidx, fb0, uacc, iacc, B, NU);
    prop3q_kernel<<<q_blocks, 256, 0, stream>>>(fb0, uidx, iidx, off, csr, invd, uacc, iacc, B, NU);

    // ---- outputs ----
    dot_kernel<<<(B * 64 + 255) / 256, 256, 0, stream>>>(uacc, iacc, out0, B);
    time_kernel<<<(B + 3) / 4, 256, 0, stream>>>(uidx, iidx, utr, itr, utt, itt, utab, itab,
                                                 W1, b1, W2, b2, out1, regpart, B);
    regreduce_kernel<<<1, 256, 0, stream>>>(regpart, out2, B);
}